// Round 7
// baseline (5921.249 us; speedup 1.0000x reference)
//
#include <hip/hip_runtime.h>
#include <hip/hip_bf16.h>

#define HWDIM 96
#define TW 16
#define THL 4                 // ty lanes per wave
#define PPT 2                 // output px rows per thread
#define TH_OUT (THL * PPT)    // 8 output rows per tile
#define NW 8                  // waves per block (hidden-channel split)
#define LWPAD 24              // padded LDS row stride (floats)

__device__ __forceinline__ float sigmoidf_fast(float x) {
    return 1.0f / (1.0f + __expf(-x));
}
__device__ __forceinline__ float tanhf_fast(float x) {
    return 2.0f / (1.0f + __expf(-2.0f * x)) - 1.0f;
}

// Repack W (4*CHID, CTOT, 3, 3) -> records of 48 floats (192B):
// dst[((wj*CTOT + ci)*4 + g)*12 + k] = W[((g*CHID + wj)*CTOT + ci)*9 + k], k<9
// (k=9..11 zero-padded) so each gate's 9 taps are 3 aligned float4 loads.
__global__ void repack_w(const float* __restrict__ W, float* __restrict__ dst,
                         int CHID, int CTOT) {
    int n = CHID * CTOT * 48;
    int i = blockIdx.x * 256 + threadIdx.x;
    if (i >= n) return;
    int k = i % 12;
    int g = (i / 12) % 4;
    int ci = (i / 48) % CTOT;
    int wj = i / (48 * CTOT);
    dst[i] = (k < 9) ? W[((g * CHID + wj) * CTOT + ci) * 9 + k] : 0.0f;
}

// Fused ConvLSTM step. Block (16,4,8)=512 thr; wave = one z-slice (64 lanes,
// 16x4), each lane computes PPT=2 vertically-adjacent px -> wave tile 16x8.
// Wave w computes hidden channels [w*CPW, (w+1)*CPW), all 4 gates (wave-local
// state update). Weights come from the repacked ws copy via vector loads
// (laundered zero offset defeats scalarization -> vmcnt domain, decoupled from
// the lgkmcnt(0) drains that stalled R3's s_load path); one gate (3 float4)
// live at a time keeps VGPRs ~60, well under the 6-waves/SIMD cap (~85).
template<int CIN_X, int CHID>
__global__ __launch_bounds__(512, 6)   // target 3 blocks/CU -> 576 blocks all resident
void convlstm_step(const float* __restrict__ x, long x_bstride,
                   const float* __restrict__ h_prev, long h_bstride, int h_zero,
                   const float* __restrict__ Wr, const float* __restrict__ bias,
                   float* __restrict__ c_state,
                   float* __restrict__ h_out, long hout_bstride) {
    constexpr int CTOT = CIN_X + CHID;
    constexpr int CPW = CHID / NW;     // hidden channels per wave
    constexpr int LH = TH_OUT + 2;     // 10 rows incl. halo
    constexpr int LW = TW + 2;         // 18 cols incl. halo

    __shared__ float tile[CTOT][LH][LWPAD];
    __shared__ int zero_sh[2];

    const int tx = threadIdx.x;        // 0..15
    const int ty = threadIdx.y;        // 0..3
    const int tid = threadIdx.z * 64 + ty * 16 + tx;
    if (tid < 2) zero_sh[tid] = 0;
    const int x0 = blockIdx.x * TW;
    const int y0 = blockIdx.y * TH_OUT;
    const int b = blockIdx.z;
    const int w = __builtin_amdgcn_readfirstlane(threadIdx.z);

    const float* xb = x + (long)b * x_bstride;
    const float* hb = h_prev + (long)b * h_bstride;

    // ---- stage input tile (with zero halo) into LDS ----
    constexpr int TILE_N = CTOT * LH * LW;
    for (int i = tid; i < TILE_N; i += 512) {
        int c = i / (LH * LW);
        int rem = i % (LH * LW);
        int r = rem / LW;
        int cc = rem % LW;
        int gy = y0 + r - 1;
        int gx = x0 + cc - 1;
        float v = 0.0f;
        if ((unsigned)gy < (unsigned)HWDIM && (unsigned)gx < (unsigned)HWDIM) {
            if (c < CIN_X) {
                v = xb[(long)c * (HWDIM * HWDIM) + gy * HWDIM + gx];
            } else if (!h_zero) {
                v = hb[(long)(c - CIN_X) * (HWDIM * HWDIM) + gy * HWDIM + gx];
            }
        }
        tile[c][r][cc] = v;
    }
    __syncthreads();

    // laundered zero: lane-indexed LDS read -> divergence-marked -> weight
    // addresses stay in VGPRs -> global_load_dwordx4, not s_load
    const int zoff = zero_sh[tx & 1];

    // ---- accumulators: CPW hidden ch x 4 gates x 2 px ----
    float acc[CPW][4][PPT];
#pragma unroll
    for (int j = 0; j < CPW; ++j) {
        int gc = w * CPW + j;
#pragma unroll
        for (int py = 0; py < PPT; ++py) {
            acc[j][0][py] = bias[gc];
            acc[j][1][py] = bias[CHID + gc];
            acc[j][2][py] = bias[2 * CHID + gc];
            acc[j][3][py] = bias[3 * CHID + gc];
        }
    }

#pragma unroll 1
    for (int ci = 0; ci < CTOT; ++ci) {
        // 4 input rows x 3 cols from LDS (covers both px of this lane)
        float in[PPT + 2][3];
#pragma unroll
        for (int r = 0; r < PPT + 2; ++r)
#pragma unroll
            for (int cc = 0; cc < 3; ++cc)
                in[r][cc] = tile[ci][PPT * ty + r][tx + cc];

#pragma unroll
        for (int j = 0; j < CPW; ++j) {
            const int rec = (w * CPW + j) * CTOT + ci;   // wave-uniform
            const float4* wp = reinterpret_cast<const float4*>(Wr)
                             + ((long)rec * 12 + zoff);  // zoff laundered 0
#pragma unroll
            for (int g = 0; g < 4; ++g) {
                float4 q0 = wp[g * 3 + 0];
                float4 q1 = wp[g * 3 + 1];
                float4 q2 = wp[g * 3 + 2];
                const float wf[9] = {q0.x, q0.y, q0.z, q0.w,
                                     q1.x, q1.y, q1.z, q1.w, q2.x};
#pragma unroll
                for (int kr = 0; kr < 3; ++kr)
#pragma unroll
                    for (int kc = 0; kc < 3; ++kc) {
                        float wgt = wf[kr * 3 + kc];
#pragma unroll
                        for (int py = 0; py < PPT; ++py)
                            acc[j][g][py] = fmaf(in[py + kr][kc], wgt, acc[j][g][py]);
                    }
            }
        }
    }

    // ---- gates + state update (wave-local channels, 2 px per lane) ----
    float* cb = c_state + (long)b * (CHID * HWDIM * HWDIM);
    float* ho = h_out + (long)b * hout_bstride;
#pragma unroll
    for (int j = 0; j < CPW; ++j) {
        int hc = w * CPW + j;
#pragma unroll
        for (int py = 0; py < PPT; ++py) {
            float si = sigmoidf_fast(acc[j][0][py]);
            float sf = sigmoidf_fast(acc[j][1][py]);
            float so = sigmoidf_fast(acc[j][2][py]);
            float tg = tanhf_fast(acc[j][3][py]);
            long ofs = (long)hc * (HWDIM * HWDIM)
                     + (y0 + PPT * ty + py) * HWDIM + (x0 + tx);
            float c_old = h_zero ? 0.0f : cb[ofs];
            float cn = sf * c_old + si * tg;
            float hn = so * tanhf_fast(cn);
            cb[ofs] = cn;
            ho[ofs] = hn;
        }
    }
}

extern "C" void kernel_launch(void* const* d_in, const int* in_sizes, int n_in,
                              void* d_out_v, int out_size, void* d_ws, size_t ws_size,
                              hipStream_t stream) {
    const float* x  = (const float*)d_in[0];
    const float* W1 = (const float*)d_in[1];
    const float* b1 = (const float*)d_in[2];
    const float* W2 = (const float*)d_in[3];
    const float* b2 = (const float*)d_in[4];
    const float* W3 = (const float*)d_in[5];
    const float* b3 = (const float*)d_in[6];
    float* out = (float*)d_out_v;
    float* ws = (float*)d_ws;

    const int HW2 = HWDIM * HWDIM;  // 9216
    const int B = 8, T = 24;

    // ---- workspace layout (floats), 16B-aligned blocks ----
    const int NW1 = 16 * 32 * 48;   // 24576 repacked W1 (padded)
    const int NW2 = 8  * 24 * 48;   // 9216  repacked W2
    const int NW3 = 16 * 24 * 48;   // 18432 repacked W3
    float* wr1 = ws;
    float* wr2 = wr1 + NW1;
    float* wr3 = wr2 + NW2;
    float* c1  = wr3 + NW3;                   // 8*16*9216
    float* c2  = c1 + (long)B * 16 * HW2;     // 8*8*9216
    float* c3  = c2 + (long)B * 8 * HW2;      // 8*16*9216
    float* o1a = c3 + (long)B * 16 * HW2;
    float* o1b = o1a + (long)B * 16 * HW2;
    float* o2a = o1b + (long)B * 16 * HW2;
    float* o2b = o2a + (long)B * 8 * HW2;
    float* out1buf[2] = {o1a, o1b};
    float* out2buf[2] = {o2a, o2b};

    // ---- repack weights into per-gate padded 12-float records ----
    repack_w<<<dim3((NW1 + 255) / 256), dim3(256), 0, stream>>>(W1, wr1, 16, 32);
    repack_w<<<dim3((NW2 + 255) / 256), dim3(256), 0, stream>>>(W2, wr2, 8, 24);
    repack_w<<<dim3((NW3 + 255) / 256), dim3(256), 0, stream>>>(W3, wr3, 16, 24);

    dim3 grid(HWDIM / TW, HWDIM / TH_OUT, B);   // (6, 12, 8) = 576 blocks
    dim3 blk(TW, THL, NW);                      // (16, 4, 8) = 512 threads

    for (int t = 0; t < T; ++t) {
        int p = t & 1, q = p ^ 1;
        // Layer 1: x_t from input seq, h from out1[prev]
        convlstm_step<16, 16><<<grid, blk, 0, stream>>>(
            x + (long)t * 16 * HW2, (long)T * 16 * HW2,
            out1buf[q], (long)16 * HW2, t == 0,
            wr1, b1, c1,
            out1buf[p], (long)16 * HW2);
        // Layer 2: x = out1[t], h from out2[prev]
        convlstm_step<16, 8><<<grid, blk, 0, stream>>>(
            out1buf[p], (long)16 * HW2,
            out2buf[q], (long)8 * HW2, t == 0,
            wr2, b2, c2,
            out2buf[p], (long)8 * HW2);
        // Layer 3: x = out2[t], h from d_out at t-1, h_out -> d_out at t
        convlstm_step<8, 16><<<grid, blk, 0, stream>>>(
            out2buf[p], (long)8 * HW2,
            (t == 0) ? out : out + (long)(t - 1) * 16 * HW2, (long)T * 16 * HW2, t == 0,
            wr3, b3, c3,
            out + (long)t * 16 * HW2, (long)T * 16 * HW2);
    }

    // append final bottleneck states: h2 = out2 written at t=23 (odd -> buf[1]), c2
    long n3 = (long)B * T * 16 * HW2;            // 28,311,552
    long nh2 = (long)B * 8 * HW2;                // 589,824
    hipMemcpyAsync(out + n3, out2buf[1], nh2 * sizeof(float),
                   hipMemcpyDeviceToDevice, stream);
    hipMemcpyAsync(out + n3 + nh2, c2, nh2 * sizeof(float),
                   hipMemcpyDeviceToDevice, stream);
}

// Round 8
// 3006.280 us; speedup vs baseline: 1.9696x; 1.9696x over previous
//
#include <hip/hip_runtime.h>
#include <hip/hip_bf16.h>

#define HWDIM 96
#define TW 16
#define THL 4                 // ty lanes per wave
#define PPT 2                 // output px rows per thread
#define TH_OUT (THL * PPT)    // 8 output rows per tile
#define NWAVE 4               // waves per block
#define LWPAD 20              // padded LDS row stride (floats)

__device__ __forceinline__ float sigmoidf_fast(float x) {
    return 1.0f / (1.0f + __expf(-x));
}
__device__ __forceinline__ float tanhf_fast(float x) {
    return 2.0f / (1.0f + __expf(-2.0f * x)) - 1.0f;
}

// Repack W (4*CHID, CTOT, 3, 3) -> records of 48 floats (192B):
// dst[((wj*CTOT + ci)*4 + g)*12 + k] = W[((g*CHID + wj)*CTOT + ci)*9 + k], k<9
// (k=9..11 zero-padded). One (hidden-ch, ci) record = 48 floats = 3x s_load_dwordx16.
__global__ void repack_w(const float* __restrict__ W, float* __restrict__ dst,
                         int CHID, int CTOT) {
    int n = CHID * CTOT * 48;
    int i = blockIdx.x * 256 + threadIdx.x;
    if (i >= n) return;
    int k = i % 12;
    int g = (i / 12) % 4;
    int ci = (i / 48) % CTOT;
    int wj = i / (48 * CTOT);
    dst[i] = (k < 9) ? W[((g * CHID + wj) * CTOT + ci) * 9 + k] : 0.0f;
}

// Fused ConvLSTM step. Block (16,4,4)=256 thr; wave = one z-slice (64 lanes,
// 16x4), each lane computes PPT=2 vertically-adjacent px -> spatial tile 16x8.
// blockIdx.z = b*2 + grp: channel-group split across blocks so the 4 waves of
// a block share a CHID/2 weight slice (shrinks per-CU scalar-cache working set
// ~4x vs R3's 8 distinct slices -> K$ hits). Weights stay on the SCALAR path:
// uniform s_load, consumed as the SGPR operand of v_fma_f32 (never in VGPRs).
// Wave w handles hidden channels grp*CHID/2 + [w*CPW, (w+1)*CPW).
template<int CIN_X, int CHID>
__global__ __launch_bounds__(256)
void convlstm_step(const float* __restrict__ x, long x_bstride,
                   const float* __restrict__ h_prev, long h_bstride, int h_zero,
                   const float* __restrict__ Wr, const float* __restrict__ bias,
                   float* __restrict__ c_state,
                   float* __restrict__ h_out, long hout_bstride) {
    constexpr int CTOT = CIN_X + CHID;
    constexpr int CGRP = CHID / 2;        // channels per block
    constexpr int CPW = CGRP / NWAVE;     // hidden channels per wave (>=1)
    constexpr int LH = TH_OUT + 2;        // 10 rows incl. halo
    constexpr int LW = TW + 2;            // 18 cols incl. halo

    __shared__ float tile[CTOT][LH][LWPAD];

    const int tx = threadIdx.x;        // 0..15
    const int ty = threadIdx.y;        // 0..3
    const int tid = threadIdx.z * 64 + ty * 16 + tx;
    const int x0 = blockIdx.x * TW;
    const int y0 = blockIdx.y * TH_OUT;
    const int b = blockIdx.z >> 1;
    const int grp = blockIdx.z & 1;
    const int w = __builtin_amdgcn_readfirstlane(threadIdx.z);

    const float* xb = x + (long)b * x_bstride;
    const float* hb = h_prev + (long)b * h_bstride;

    // ---- stage input tile (with zero halo) into LDS, 256 threads ----
    constexpr int TILE_N = CTOT * LH * LW;
    for (int i = tid; i < TILE_N; i += 256) {
        int c = i / (LH * LW);
        int rem = i % (LH * LW);
        int r = rem / LW;
        int cc = rem % LW;
        int gy = y0 + r - 1;
        int gx = x0 + cc - 1;
        float v = 0.0f;
        if ((unsigned)gy < (unsigned)HWDIM && (unsigned)gx < (unsigned)HWDIM) {
            if (c < CIN_X) {
                v = xb[(long)c * (HWDIM * HWDIM) + gy * HWDIM + gx];
            } else if (!h_zero) {
                v = hb[(long)(c - CIN_X) * (HWDIM * HWDIM) + gy * HWDIM + gx];
            }
        }
        tile[c][r][cc] = v;
    }
    __syncthreads();

    // ---- accumulators: CPW hidden ch x 4 gates x 2 px ----
    float acc[CPW][4][PPT];
#pragma unroll
    for (int j = 0; j < CPW; ++j) {
        int wj = grp * CGRP + w * CPW + j;
#pragma unroll
        for (int py = 0; py < PPT; ++py) {
            acc[j][0][py] = bias[wj];
            acc[j][1][py] = bias[CHID + wj];
            acc[j][2][py] = bias[2 * CHID + wj];
            acc[j][3][py] = bias[3 * CHID + wj];
        }
    }

#pragma unroll 2
    for (int ci = 0; ci < CTOT; ++ci) {
        // 4 input rows x 3 cols from LDS (covers both px of this lane)
        float in[PPT + 2][3];
#pragma unroll
        for (int r = 0; r < PPT + 2; ++r)
#pragma unroll
            for (int cc = 0; cc < 3; ++cc)
                in[r][cc] = tile[ci][PPT * ty + r][tx + cc];

#pragma unroll
        for (int j = 0; j < CPW; ++j) {
            const int wj = grp * CGRP + w * CPW + j;        // wave-uniform
            const float* wrec = Wr + ((long)(wj * CTOT + ci)) * 48;  // s_load x3 dwordx16
#pragma unroll
            for (int g = 0; g < 4; ++g)
#pragma unroll
                for (int kr = 0; kr < 3; ++kr)
#pragma unroll
                    for (int kc = 0; kc < 3; ++kc) {
                        float wgt = wrec[g * 12 + kr * 3 + kc];  // SGPR operand
#pragma unroll
                        for (int py = 0; py < PPT; ++py)
                            acc[j][g][py] = fmaf(in[py + kr][kc], wgt, acc[j][g][py]);
                    }
        }
    }

    // ---- gates + state update (wave-local channels, 2 px per lane) ----
    float* cb = c_state + (long)b * (CHID * HWDIM * HWDIM);
    float* ho = h_out + (long)b * hout_bstride;
#pragma unroll
    for (int j = 0; j < CPW; ++j) {
        int wj = grp * CGRP + w * CPW + j;
#pragma unroll
        for (int py = 0; py < PPT; ++py) {
            float si = sigmoidf_fast(acc[j][0][py]);
            float sf = sigmoidf_fast(acc[j][1][py]);
            float so = sigmoidf_fast(acc[j][2][py]);
            float tg = tanhf_fast(acc[j][3][py]);
            long ofs = (long)wj * (HWDIM * HWDIM)
                     + (y0 + PPT * ty + py) * HWDIM + (x0 + tx);
            float c_old = h_zero ? 0.0f : cb[ofs];
            float cn = sf * c_old + si * tg;
            float hn = so * tanhf_fast(cn);
            cb[ofs] = cn;
            ho[ofs] = hn;
        }
    }
}

extern "C" void kernel_launch(void* const* d_in, const int* in_sizes, int n_in,
                              void* d_out_v, int out_size, void* d_ws, size_t ws_size,
                              hipStream_t stream) {
    const float* x  = (const float*)d_in[0];
    const float* W1 = (const float*)d_in[1];
    const float* b1 = (const float*)d_in[2];
    const float* W2 = (const float*)d_in[3];
    const float* b2 = (const float*)d_in[4];
    const float* W3 = (const float*)d_in[5];
    const float* b3 = (const float*)d_in[6];
    float* out = (float*)d_out_v;
    float* ws = (float*)d_ws;

    const int HW2 = HWDIM * HWDIM;  // 9216
    const int B = 8, T = 24;

    // ---- workspace layout (floats), 16B-aligned blocks ----
    const int NW1 = 16 * 32 * 48;   // 24576 repacked W1 (padded)
    const int NW2 = 8  * 24 * 48;   // 9216  repacked W2
    const int NW3 = 16 * 24 * 48;   // 18432 repacked W3
    float* wr1 = ws;
    float* wr2 = wr1 + NW1;
    float* wr3 = wr2 + NW2;
    float* c1  = wr3 + NW3;                   // 8*16*9216
    float* c2  = c1 + (long)B * 16 * HW2;     // 8*8*9216
    float* c3  = c2 + (long)B * 8 * HW2;      // 8*16*9216
    float* o1a = c3 + (long)B * 16 * HW2;
    float* o1b = o1a + (long)B * 16 * HW2;
    float* o2a = o1b + (long)B * 16 * HW2;
    float* o2b = o2a + (long)B * 8 * HW2;
    float* out1buf[2] = {o1a, o1b};
    float* out2buf[2] = {o2a, o2b};

    // ---- repack weights into per-gate padded 12-float records ----
    repack_w<<<dim3((NW1 + 255) / 256), dim3(256), 0, stream>>>(W1, wr1, 16, 32);
    repack_w<<<dim3((NW2 + 255) / 256), dim3(256), 0, stream>>>(W2, wr2, 8, 24);
    repack_w<<<dim3((NW3 + 255) / 256), dim3(256), 0, stream>>>(W3, wr3, 16, 24);

    dim3 grid(HWDIM / TW, HWDIM / TH_OUT, B * 2);   // (6, 12, 16) = 1152 blocks
    dim3 blk(TW, THL, NWAVE);                       // (16, 4, 4) = 256 threads

    for (int t = 0; t < T; ++t) {
        int p = t & 1, q = p ^ 1;
        // Layer 1: x_t from input seq, h from out1[prev]
        convlstm_step<16, 16><<<grid, blk, 0, stream>>>(
            x + (long)t * 16 * HW2, (long)T * 16 * HW2,
            out1buf[q], (long)16 * HW2, t == 0,
            wr1, b1, c1,
            out1buf[p], (long)16 * HW2);
        // Layer 2: x = out1[t], h from out2[prev]
        convlstm_step<16, 8><<<grid, blk, 0, stream>>>(
            out1buf[p], (long)16 * HW2,
            out2buf[q], (long)8 * HW2, t == 0,
            wr2, b2, c2,
            out2buf[p], (long)8 * HW2);
        // Layer 3: x = out2[t], h from d_out at t-1, h_out -> d_out at t
        convlstm_step<8, 16><<<grid, blk, 0, stream>>>(
            out2buf[p], (long)8 * HW2,
            (t == 0) ? out : out + (long)(t - 1) * 16 * HW2, (long)T * 16 * HW2, t == 0,
            wr3, b3, c3,
            out + (long)t * 16 * HW2, (long)T * 16 * HW2);
    }

    // append final bottleneck states: h2 = out2 written at t=23 (odd -> buf[1]), c2
    long n3 = (long)B * T * 16 * HW2;            // 28,311,552
    long nh2 = (long)B * 8 * HW2;                // 589,824
    hipMemcpyAsync(out + n3, out2buf[1], nh2 * sizeof(float),
                   hipMemcpyDeviceToDevice, stream);
    hipMemcpyAsync(out + n3 + nh2, c2, nh2 * sizeof(float),
                   hipMemcpyDeviceToDevice, stream);
}

// Round 9
// 1823.476 us; speedup vs baseline: 3.2472x; 1.6487x over previous
//
#include <hip/hip_runtime.h>
#include <hip/hip_bf16.h>

#define HWDIM 96
#define HW2 (HWDIM * HWDIM)

using bf16x8 = __attribute__((ext_vector_type(8))) short;
using f32x4  = __attribute__((ext_vector_type(4))) float;

__device__ __forceinline__ float sigmoidf_fast(float x) {
    return 1.0f / (1.0f + __expf(-x));
}
__device__ __forceinline__ float tanhf_fast(float x) {
    return 2.0f / (1.0f + __expf(-2.0f * x)) - 1.0f;
}
__device__ __forceinline__ unsigned short f2bf(float f) {
    unsigned u = __float_as_uint(f);
    unsigned r = (u + 0x7FFFu + ((u >> 16) & 1u)) >> 16;   // RNE
    return (unsigned short)r;
}
__device__ __forceinline__ float bf2f(unsigned short h) {
    return __uint_as_float(((unsigned)h) << 16);
}

// Repack W (4*CHID, CTOT, 3, 3) fp32 -> hi/lo bf16 arrays laid out
// [gg][tap][row16][ch32], row = hcl*4 + gate (so MFMA D-rows 4q+reg map to
// (hidden q, gate reg)), ch padded to 32 with zeros.
__global__ void repack_w(const float* __restrict__ W,
                         unsigned short* __restrict__ dhi,
                         unsigned short* __restrict__ dlo,
                         int CHID, int CTOT, int NG) {
    int n = NG * 9 * 16 * 32;
    int i = blockIdx.x * 256 + threadIdx.x;
    if (i >= n) return;
    int ch   = i & 31;
    int row  = (i >> 5) & 15;
    int tmp  = i >> 9;
    int tap  = tmp % 9;
    int gg   = tmp / 9;
    int gate = row & 3;
    int hc   = gg * 4 + (row >> 2);
    float w = 0.0f;
    if (ch < CTOT) w = W[((gate * CHID + hc) * CTOT + ch) * 9 + tap];
    unsigned short h = f2bf(w);
    dhi[i] = h;
    dlo[i] = f2bf(w - bf2f(h));
}

// Fused ConvLSTM step via implicit-GEMM MFMA (bf16x3 split).
// Block 512 thr = 8 waves over a 16x8 px tile (halo 18x10), all channels
// padded to 32. Wave = (gate-group gg of 4 hidden ch) x (px partition).
// Per subtile (16 px row): 9 taps x 3 mfma_f32_16x16x32_bf16 accumulating
// z[16 gate-rows x 16 px]; lane-local epilogue (acc[g] = gate g of hidden
// channel gg*4+(lane>>4) at px col lane&15).
template<int CIN_X, int CHID>
__global__ __launch_bounds__(512, 4)
void convlstm_mfma(const float* __restrict__ x, long x_bstride,
                   const float* __restrict__ h_prev, long h_bstride, int h_zero,
                   const unsigned short* __restrict__ Whi,
                   const unsigned short* __restrict__ Wlo,
                   const float* __restrict__ bias,
                   float* __restrict__ c_state,
                   float* __restrict__ h_out, long hout_bstride) {
    constexpr int CTOT = CIN_X + CHID;
    constexpr int NG = CHID / 4;          // gate-groups (16 rows each)
    constexpr int SPW = NG;               // subtiles per wave (8 / PARTS)
    static_assert(8 % NG == 0, "");

    __shared__ bf16x8 BH[4][10][18];      // [ch-octet][y][x][8ch] hi
    __shared__ bf16x8 BL[4][10][18];      // lo

    const int tid = threadIdx.x;
    const int lane = tid & 63;
    const int wid = tid >> 6;
    const int x0 = blockIdx.x * 16;
    const int y0 = blockIdx.y * 8;
    const int b = blockIdx.z;

    const float* xb = x + (long)b * x_bstride;
    const float* hb = h_prev + (long)b * h_bstride;

    // ---- stage input tile -> bf16 hi/lo LDS (zero halo + zero ch-pad) ----
    for (int i = tid; i < 32 * 180; i += 512) {
        int c = i / 180;
        int rem = i - c * 180;
        int yy = rem / 18;
        int xx = rem - yy * 18;
        int gy = y0 + yy - 1;
        int gx = x0 + xx - 1;
        float v = 0.0f;
        if ((unsigned)gy < (unsigned)HWDIM && (unsigned)gx < (unsigned)HWDIM) {
            if (c < CIN_X) {
                v = xb[(long)c * HW2 + gy * HWDIM + gx];
            } else if (c < CTOT && !h_zero) {
                v = hb[(long)(c - CIN_X) * HW2 + gy * HWDIM + gx];
            }
        }
        unsigned short hv = f2bf(v);
        ((unsigned short*)&BH[c >> 3][yy][xx])[c & 7] = hv;
        ((unsigned short*)&BL[c >> 3][yy][xx])[c & 7] = f2bf(v - bf2f(hv));
    }
    __syncthreads();

    const int gg = wid & (NG - 1);        // gate-group
    const int ph = wid / NG;              // px partition
    const int col = lane & 15;            // A-row / B-col / D-col
    const int q = lane >> 4;              // k-octet / D-row-quad

    // ---- hoist A fragments: 9 taps x (hi,lo), 16B per lane each ----
    bf16x8 Ah[9], Al[9];
#pragma unroll
    for (int tap = 0; tap < 9; ++tap) {
        long aofs = (((long)(gg * 9 + tap) * 16 + col) << 5) + q * 8;
        Ah[tap] = *(const bf16x8*)(Whi + aofs);
        Al[tap] = *(const bf16x8*)(Wlo + aofs);
    }

    const int hc = gg * 4 + q;            // this lane's hidden channel
    const float bi = bias[0 * CHID + hc];
    const float bf_ = bias[1 * CHID + hc];
    const float bo = bias[2 * CHID + hc];
    const float bg = bias[3 * CHID + hc];

    float* cb = c_state + (long)b * (CHID * HW2);
    float* ho = h_out + (long)b * hout_bstride;

#pragma unroll 1
    for (int j = 0; j < SPW; ++j) {
        const int s = ph * SPW + j;       // px row within tile (0..7)
        f32x4 acc = {0.0f, 0.0f, 0.0f, 0.0f};
#pragma unroll
        for (int tap = 0; tap < 9; ++tap) {
            const int kr = tap / 3, kc = tap % 3;
            bf16x8 bh = BH[q][s + kr][col + kc];
            bf16x8 bl = BL[q][s + kr][col + kc];
            acc = __builtin_amdgcn_mfma_f32_16x16x32_bf16(Ah[tap], bh, acc, 0, 0, 0);
            acc = __builtin_amdgcn_mfma_f32_16x16x32_bf16(Ah[tap], bl, acc, 0, 0, 0);
            acc = __builtin_amdgcn_mfma_f32_16x16x32_bf16(Al[tap], bh, acc, 0, 0, 0);
        }
        // ---- lane-local LSTM pointwise update ----
        float si = sigmoidf_fast(acc[0] + bi);
        float sf = sigmoidf_fast(acc[1] + bf_);
        float so = sigmoidf_fast(acc[2] + bo);
        float tg = tanhf_fast(acc[3] + bg);
        long ofs = (long)hc * HW2 + (y0 + s) * HWDIM + (x0 + col);
        float c_old = h_zero ? 0.0f : cb[ofs];
        float cn = sf * c_old + si * tg;
        float hn = so * tanhf_fast(cn);
        cb[ofs] = cn;
        ho[ofs] = hn;
    }
}

extern "C" void kernel_launch(void* const* d_in, const int* in_sizes, int n_in,
                              void* d_out_v, int out_size, void* d_ws, size_t ws_size,
                              hipStream_t stream) {
    const float* x  = (const float*)d_in[0];
    const float* W1 = (const float*)d_in[1];
    const float* b1 = (const float*)d_in[2];
    const float* W2 = (const float*)d_in[3];
    const float* b2 = (const float*)d_in[4];
    const float* W3 = (const float*)d_in[5];
    const float* b3 = (const float*)d_in[6];
    float* out = (float*)d_out_v;

    const int B = 8, T = 24;

    // ---- ws layout: repacked bf16 weights (ushort), then fp32 state ----
    const int N1 = 4 * 9 * 16 * 32;   // 18432 (L1)
    const int N2 = 2 * 9 * 16 * 32;   // 9216  (L2)
    const int N3 = 4 * 9 * 16 * 32;   // 18432 (L3)
    unsigned short* wp1h = (unsigned short*)d_ws;
    unsigned short* wp1l = wp1h + N1;
    unsigned short* wp2h = wp1l + N1;
    unsigned short* wp2l = wp2h + N2;
    unsigned short* wp3h = wp2l + N2;
    unsigned short* wp3l = wp3h + N3;
    float* fbase = (float*)(wp3l + N3);   // 92160 ushorts = 184320 B, 16B-aligned
    float* c1  = fbase;                       // 8*16*HW2
    float* c2  = c1 + (long)B * 16 * HW2;     // 8*8*HW2
    float* c3  = c2 + (long)B * 8 * HW2;      // 8*16*HW2
    float* o1a = c3 + (long)B * 16 * HW2;
    float* o1b = o1a + (long)B * 16 * HW2;
    float* o2a = o1b + (long)B * 16 * HW2;
    float* o2b = o2a + (long)B * 8 * HW2;
    float* out1buf[2] = {o1a, o1b};
    float* out2buf[2] = {o2a, o2b};

    repack_w<<<dim3((N1 + 255) / 256), dim3(256), 0, stream>>>(W1, wp1h, wp1l, 16, 32, 4);
    repack_w<<<dim3((N2 + 255) / 256), dim3(256), 0, stream>>>(W2, wp2h, wp2l, 8, 24, 2);
    repack_w<<<dim3((N3 + 255) / 256), dim3(256), 0, stream>>>(W3, wp3h, wp3l, 16, 24, 4);

    dim3 grid(HWDIM / 16, HWDIM / 8, B);   // (6, 12, 8) = 576 blocks
    dim3 blk(512, 1, 1);

    for (int t = 0; t < T; ++t) {
        int p = t & 1, q = p ^ 1;
        // Layer 1: x_t from input seq, h from out1[prev]
        convlstm_mfma<16, 16><<<grid, blk, 0, stream>>>(
            x + (long)t * 16 * HW2, (long)T * 16 * HW2,
            out1buf[q], (long)16 * HW2, t == 0,
            wp1h, wp1l, b1, c1,
            out1buf[p], (long)16 * HW2);
        // Layer 2: x = out1[t], h from out2[prev]
        convlstm_mfma<16, 8><<<grid, blk, 0, stream>>>(
            out1buf[p], (long)16 * HW2,
            out2buf[q], (long)8 * HW2, t == 0,
            wp2h, wp2l, b2, c2,
            out2buf[p], (long)8 * HW2);
        // Layer 3: x = out2[t], h from d_out at t-1, h_out -> d_out at t
        convlstm_mfma<8, 16><<<grid, blk, 0, stream>>>(
            out2buf[p], (long)8 * HW2,
            (t == 0) ? out : out + (long)(t - 1) * 16 * HW2, (long)T * 16 * HW2, t == 0,
            wp3h, wp3l, b3, c3,
            out + (long)t * 16 * HW2, (long)T * 16 * HW2);
    }

    // append final bottleneck states: h2 = out2 written at t=23 (odd -> buf[1]), c2
    long n3 = (long)B * T * 16 * HW2;            // 28,311,552
    long nh2 = (long)B * 8 * HW2;                // 589,824
    hipMemcpyAsync(out + n3, out2buf[1], nh2 * sizeof(float),
                   hipMemcpyDeviceToDevice, stream);
    hipMemcpyAsync(out + n3 + nh2, c2, nh2 * sizeof(float),
                   hipMemcpyDeviceToDevice, stream);
}

// Round 10
// 1518.770 us; speedup vs baseline: 3.8987x; 1.2006x over previous
//
#include <hip/hip_runtime.h>
#include <hip/hip_bf16.h>

#define HWDIM 96
#define HW2 (HWDIM * HWDIM)

using bf16x8 = __attribute__((ext_vector_type(8))) short;
using f32x4  = __attribute__((ext_vector_type(4))) float;

__device__ __forceinline__ float sigmoidf_fast(float x) {
    return 1.0f / (1.0f + __expf(-x));
}
__device__ __forceinline__ float tanhf_fast(float x) {
    return 2.0f / (1.0f + __expf(-2.0f * x)) - 1.0f;
}
__device__ __forceinline__ unsigned short f2bf(float f) {
    unsigned u = __float_as_uint(f);
    unsigned r = (u + 0x7FFFu + ((u >> 16) & 1u)) >> 16;   // RNE
    return (unsigned short)r;
}
__device__ __forceinline__ float bf2f(unsigned short h) {
    return __uint_as_float(((unsigned)h) << 16);
}

// Repack W (4*CHID, CTOT, 3, 3) fp32 -> hi/lo bf16 arrays laid out
// [gg][tap][row16][ch32], row = hcl*4 + gate (so MFMA D-rows 4q+reg map to
// (hidden q, gate reg)), ch padded to 32 with zeros.
__global__ void repack_w(const float* __restrict__ W,
                         unsigned short* __restrict__ dhi,
                         unsigned short* __restrict__ dlo,
                         int CHID, int CTOT, int NG) {
    int n = NG * 9 * 16 * 32;
    int i = blockIdx.x * 256 + threadIdx.x;
    if (i >= n) return;
    int ch   = i & 31;
    int row  = (i >> 5) & 15;
    int tmp  = i >> 9;
    int tap  = tmp % 9;
    int gg   = tmp / 9;
    int gate = row & 3;
    int hc   = gg * 4 + (row >> 2);
    float w = 0.0f;
    if (ch < CTOT) w = W[((gate * CHID + hc) * CTOT + ch) * 9 + tap];
    unsigned short h = f2bf(w);
    dhi[i] = h;
    dlo[i] = f2bf(w - bf2f(h));
}

// Fused ConvLSTM step via implicit-GEMM MFMA (bf16x3 split).
// Block 512 thr = 8 waves over a 16x8 px tile (halo 18x10), channels padded
// to 32. Wave = (gate-group gg of 4 hidden ch) x (px partition ph).
// Staging: octet-granular — 8 coalesced dword loads -> pack -> 2x ds_write_b128
// (CIN_X is a multiple of 8 in all layers, so an octet never straddles x/h).
// Compute: per px-row subtile, 9 taps x {hh,hl,lh} MFMAs into 3 INDEPENDENT
// acc chains (breaks the R9 27-deep dependent-MFMA chain), summed in epilogue.
// Epilogue lane-local: acc reg g = gate g of hidden ch gg*4+(lane>>4) at px
// col lane&15 (m89 C/D layout, bench-verified in R9).
template<int CIN_X, int CHID>
__global__ __launch_bounds__(512, 4)
void convlstm_mfma(const float* __restrict__ x, long x_bstride,
                   const float* __restrict__ h_prev, long h_bstride, int h_zero,
                   const unsigned short* __restrict__ Whi,
                   const unsigned short* __restrict__ Wlo,
                   const float* __restrict__ bias,
                   float* __restrict__ c_state,
                   float* __restrict__ h_out, long hout_bstride) {
    constexpr int CTOT = CIN_X + CHID;
    constexpr int NG = CHID / 4;          // gate-groups (16 gate-rows each)
    constexpr int PARTS = 8 / NG;         // px partitions
    constexpr int SPW = 8 / PARTS;        // px rows per wave
    static_assert(CIN_X % 8 == 0, "octet staging needs CIN_X % 8 == 0");

    __shared__ bf16x8 BH[4][10][18];      // [ch-octet][y][x][8ch] hi
    __shared__ bf16x8 BL[4][10][18];      // lo

    const int tid = threadIdx.x;
    const int lane = tid & 63;
    const int wid = tid >> 6;
    const int x0 = blockIdx.x * 16;
    const int y0 = blockIdx.y * 8;
    const int b = blockIdx.z;

    const float* xb = x + (long)b * x_bstride;
    const float* hb = h_prev + (long)b * h_bstride;

    // ---- octet staging: 720 = 4 octets x 180 px positions ----
    for (int i = tid; i < 720; i += 512) {
        int oct = i / 180;
        int rem = i - oct * 180;
        int yy = rem / 18;
        int xx = rem - yy * 18;
        int gy = y0 + yy - 1;
        int gx = x0 + xx - 1;
        bool inb = ((unsigned)gy < (unsigned)HWDIM) && ((unsigned)gx < (unsigned)HWDIM);
        int c0 = oct * 8;
        const float* src;
        bool has;
        if (c0 < CIN_X)      { src = xb + (long)c0 * HW2;            has = true; }
        else if (c0 < CTOT)  { src = hb + (long)(c0 - CIN_X) * HW2;  has = !h_zero; }
        else                 { src = xb;                             has = false; }
        has = has && inb;
        long off = (long)gy * HWDIM + gx;
        bf16x8 vh, vl;
#pragma unroll
        for (int k = 0; k < 8; ++k) {
            float v = has ? src[(long)k * HW2 + off] : 0.0f;
            unsigned short hv = f2bf(v);
            ((unsigned short*)&vh)[k] = hv;
            ((unsigned short*)&vl)[k] = f2bf(v - bf2f(hv));
        }
        BH[oct][yy][xx] = vh;
        BL[oct][yy][xx] = vl;
    }
    __syncthreads();

    const int gg = wid & (NG - 1);        // gate-group
    const int ph = wid / NG;              // px partition
    const int col = lane & 15;            // A-row / B-col / D-col
    const int q = lane >> 4;              // k-octet / D-row-quad

    // ---- hoist A fragments: 9 taps x (hi,lo), 16B per lane each ----
    bf16x8 Ah[9], Al[9];
#pragma unroll
    for (int tap = 0; tap < 9; ++tap) {
        long aofs = (((long)(gg * 9 + tap) * 16 + col) << 5) + q * 8;
        Ah[tap] = *(const bf16x8*)(Whi + aofs);
        Al[tap] = *(const bf16x8*)(Wlo + aofs);
    }

    const int hc = gg * 4 + q;            // this lane's hidden channel
    const float bi = bias[0 * CHID + hc];
    const float bf_ = bias[1 * CHID + hc];
    const float bo = bias[2 * CHID + hc];
    const float bg = bias[3 * CHID + hc];

    float* cb = c_state + (long)b * (CHID * HW2);
    float* ho = h_out + (long)b * hout_bstride;

#pragma unroll 1
    for (int j = 0; j < SPW; ++j) {
        const int s = ph * SPW + j;       // px row within tile (0..7)
        f32x4 ahh = {0.0f, 0.0f, 0.0f, 0.0f};
        f32x4 ahl = {0.0f, 0.0f, 0.0f, 0.0f};
        f32x4 alh = {0.0f, 0.0f, 0.0f, 0.0f};
#pragma unroll
        for (int tap = 0; tap < 9; ++tap) {
            const int kr = tap / 3, kc = tap % 3;
            bf16x8 bh = BH[q][s + kr][col + kc];
            bf16x8 bl = BL[q][s + kr][col + kc];
            ahh = __builtin_amdgcn_mfma_f32_16x16x32_bf16(Ah[tap], bh, ahh, 0, 0, 0);
            ahl = __builtin_amdgcn_mfma_f32_16x16x32_bf16(Ah[tap], bl, ahl, 0, 0, 0);
            alh = __builtin_amdgcn_mfma_f32_16x16x32_bf16(Al[tap], bh, alh, 0, 0, 0);
        }
        // ---- lane-local LSTM pointwise update ----
        float zi = ahh[0] + ahl[0] + alh[0] + bi;
        float zf = ahh[1] + ahl[1] + alh[1] + bf_;
        float zo = ahh[2] + ahl[2] + alh[2] + bo;
        float zg = ahh[3] + ahl[3] + alh[3] + bg;
        float si = sigmoidf_fast(zi);
        float sf = sigmoidf_fast(zf);
        float so = sigmoidf_fast(zo);
        float tg = tanhf_fast(zg);
        long ofs = (long)hc * HW2 + (y0 + s) * HWDIM + (x0 + col);
        float c_old = h_zero ? 0.0f : cb[ofs];
        float cn = sf * c_old + si * tg;
        float hn = so * tanhf_fast(cn);
        cb[ofs] = cn;
        ho[ofs] = hn;
    }
}

extern "C" void kernel_launch(void* const* d_in, const int* in_sizes, int n_in,
                              void* d_out_v, int out_size, void* d_ws, size_t ws_size,
                              hipStream_t stream) {
    const float* x  = (const float*)d_in[0];
    const float* W1 = (const float*)d_in[1];
    const float* b1 = (const float*)d_in[2];
    const float* W2 = (const float*)d_in[3];
    const float* b2 = (const float*)d_in[4];
    const float* W3 = (const float*)d_in[5];
    const float* b3 = (const float*)d_in[6];
    float* out = (float*)d_out_v;

    const int B = 8, T = 24;

    // ---- ws layout: repacked bf16 weights (ushort), then fp32 state ----
    const int N1 = 4 * 9 * 16 * 32;   // 18432 (L1)
    const int N2 = 2 * 9 * 16 * 32;   // 9216  (L2)
    const int N3 = 4 * 9 * 16 * 32;   // 18432 (L3)
    unsigned short* wp1h = (unsigned short*)d_ws;
    unsigned short* wp1l = wp1h + N1;
    unsigned short* wp2h = wp1l + N1;
    unsigned short* wp2l = wp2h + N2;
    unsigned short* wp3h = wp2l + N2;
    unsigned short* wp3l = wp3h + N3;
    float* fbase = (float*)(wp3l + N3);   // 92160 ushorts = 184320 B, 16B-aligned
    float* c1  = fbase;                       // 8*16*HW2
    float* c2  = c1 + (long)B * 16 * HW2;     // 8*8*HW2
    float* c3  = c2 + (long)B * 8 * HW2;      // 8*16*HW2
    float* o1a = c3 + (long)B * 16 * HW2;
    float* o1b = o1a + (long)B * 16 * HW2;
    float* o2a = o1b + (long)B * 16 * HW2;
    float* o2b = o2a + (long)B * 8 * HW2;
    float* out1buf[2] = {o1a, o1b};
    float* out2buf[2] = {o2a, o2b};

    repack_w<<<dim3((N1 + 255) / 256), dim3(256), 0, stream>>>(W1, wp1h, wp1l, 16, 32, 4);
    repack_w<<<dim3((N2 + 255) / 256), dim3(256), 0, stream>>>(W2, wp2h, wp2l, 8, 24, 2);
    repack_w<<<dim3((N3 + 255) / 256), dim3(256), 0, stream>>>(W3, wp3h, wp3l, 16, 24, 4);

    dim3 grid(HWDIM / 16, HWDIM / 8, B);   // (6, 12, 8) = 576 blocks
    dim3 blk(512, 1, 1);

    for (int t = 0; t < T; ++t) {
        int p = t & 1, q = p ^ 1;
        // Layer 1: x_t from input seq, h from out1[prev]
        convlstm_mfma<16, 16><<<grid, blk, 0, stream>>>(
            x + (long)t * 16 * HW2, (long)T * 16 * HW2,
            out1buf[q], (long)16 * HW2, t == 0,
            wp1h, wp1l, b1, c1,
            out1buf[p], (long)16 * HW2);
        // Layer 2: x = out1[t], h from out2[prev]
        convlstm_mfma<16, 8><<<grid, blk, 0, stream>>>(
            out1buf[p], (long)16 * HW2,
            out2buf[q], (long)8 * HW2, t == 0,
            wp2h, wp2l, b2, c2,
            out2buf[p], (long)8 * HW2);
        // Layer 3: x = out2[t], h from d_out at t-1, h_out -> d_out at t
        convlstm_mfma<8, 16><<<grid, blk, 0, stream>>>(
            out2buf[p], (long)8 * HW2,
            (t == 0) ? out : out + (long)(t - 1) * 16 * HW2, (long)T * 16 * HW2, t == 0,
            wp3h, wp3l, b3, c3,
            out + (long)t * 16 * HW2, (long)T * 16 * HW2);
    }

    // append final bottleneck states: h2 = out2 written at t=23 (odd -> buf[1]), c2
    long n3 = (long)B * T * 16 * HW2;            // 28,311,552
    long nh2 = (long)B * 8 * HW2;                // 589,824
    hipMemcpyAsync(out + n3, out2buf[1], nh2 * sizeof(float),
                   hipMemcpyDeviceToDevice, stream);
    hipMemcpyAsync(out + n3 + nh2, c2, nh2 * sizeof(float),
                   hipMemcpyDeviceToDevice, stream);
}